// Round 18
// baseline (2232.152 us; speedup 1.0000x reference)
//
#include <hip/hip_runtime.h>
#include <hip/hip_bf16.h>
#include <cstddef>

#define NB 32      // batch
#define NP 196     // pixels
#define NE 2048    // encoder dim
#define ND 512     // decoder/att/emb dim
#define NV 32000   // vocab
#define NL 21
#define NT 20      // decode steps

typedef __attribute__((ext_vector_type(8))) short short8;   // 8 bf16 (4 VGPRs)
typedef __attribute__((ext_vector_type(4))) float f32x4;

__device__ __forceinline__ unsigned short f2b(float f) {
    __hip_bfloat16 h = __float2bfloat16(f);      // RNE
    return *reinterpret_cast<unsigned short*>(&h);
}
__device__ __forceinline__ float b2f(unsigned short u) {
    union { unsigned int i; float f; } v; v.i = (unsigned)u << 16; return v.f;
}
__device__ __forceinline__ float b2f_lo(unsigned int u) {
    union { unsigned int i; float f; } v; v.i = u << 16; return v.f;
}
__device__ __forceinline__ float b2f_hi(unsigned int u) {
    union { unsigned int i; float f; } v; v.i = u & 0xffff0000u; return v.f;
}

// ---------------- setup ----------------

__global__ void k_sort(const int* __restrict__ lens, int* __restrict__ sind, int* __restrict__ dlens,
                       int* __restrict__ rowmap, int* __restrict__ mpad)
{
    int i = threadIdx.x;
    if (i < NB) {
        int li = lens[i];
        int r = 0;
        for (int j = 0; j < NB; ++j) {
            int lj = lens[j];
            if (lj > li || (lj == li && j < i)) ++r;
        }
        sind[r] = i;
        dlens[r] = li - 1;
    }
    __syncthreads();
    if (i == 0) {
        int c = 0;
        for (int t = 0; t < NT; ++t)
            for (int b = 0; b < NB; ++b)
                if (t < dlens[b]) rowmap[c++] = t * NB + b;
        int pad = (c + 127) & ~127;                // BM=128 for preds
        for (int r = c; r < pad; ++r) rowmap[r] = -1;
        mpad[0] = pad;
    }
}

// enc (sorted) -> bf16 copy (grid 6272) — consumed by k_awe only
__global__ __launch_bounds__(256) void k_conv_enc(
    const float* __restrict__ enc, const int* __restrict__ sind,
    unsigned short* __restrict__ encB)
{
    int idx = (blockIdx.x * 256 + threadIdx.x) * 8;
    int b = idx / (NP * NE), rem = idx - b * (NP * NE);
    const float* src = enc + (size_t)sind[b] * NP * NE + rem;
    float4 a = *reinterpret_cast<const float4*>(src);
    float4 c = *reinterpret_cast<const float4*>(src + 4);
    uint4 o;
    o.x = f2b(a.x) | ((unsigned)f2b(a.y) << 16);
    o.y = f2b(a.z) | ((unsigned)f2b(a.w) << 16);
    o.z = f2b(c.x) | ((unsigned)f2b(c.y) << 16);
    o.w = f2b(c.z) | ((unsigned)f2b(c.w) << 16);
    *reinterpret_cast<uint4*>(encB + idx) = o;
}

// embS[t][b][512] = emb_W[caps[sind[b]][t]]   (grid (NT, NB))
__global__ __launch_bounds__(256) void k_emb(
    const int* __restrict__ caps, const int* __restrict__ sind,
    const float* __restrict__ emb_W, float* __restrict__ embS)
{
    int t = blockIdx.x, b = blockIdx.y;
    const float* src = emb_W + (size_t)caps[sind[b] * NL + t] * ND;
    float* dst = embS + ((size_t)t * NB + b) * ND;
    int i = threadIdx.x * 2;
    *reinterpret_cast<float2*>(dst + i) = *reinterpret_cast<const float2*>(src + i);
}

__global__ __launch_bounds__(256) void k_mean(const float* __restrict__ enc, const int* __restrict__ sind,
                                              float* __restrict__ mean_enc)
{
    int b = blockIdx.y;
    int k = blockIdx.x * 256 + threadIdx.x;
    const float* e = enc + (size_t)sind[b] * NP * NE + k;
    float s0 = 0.f, s1 = 0.f, s2 = 0.f, s3 = 0.f;
    for (int p = 0; p < NP; p += 4) {
        s0 += e[(size_t)(p + 0) * NE];
        s1 += e[(size_t)(p + 1) * NE];
        s2 += e[(size_t)(p + 2) * NE];
        s3 += e[(size_t)(p + 3) * NE];
    }
    mean_enc[(size_t)b * NE + k] = (s0 + s1 + s2 + s3) * (1.0f / NP);
}

__global__ __launch_bounds__(256) void k_zero(const int* __restrict__ dlens, float* __restrict__ out)
{
    int b = blockIdx.x / NT, t = blockIdx.x % NT;
    if (t < dlens[b]) return;
    float4 z = {0.f, 0.f, 0.f, 0.f};
    float4* row = (float4*)(out + ((size_t)b * NT + t) * NV);
    for (int i = threadIdx.x; i < NV / 4; i += 256) row[i] = z;
}

// ---------------- shared tile body: C_part[32][64] = A[32][K] @ W^T (uniform W) ----------------
__device__ __forceinline__ void tile_body_uniW(
    const float* __restrict__ A, int lda, const float* __restrict__ W, int wstride,
    int n0, int kbeg, int kend, float* As, float (*Ws)[33], float acc[4][2],
    int tid)
{
    int lb = tid / 8, lkq = tid % 8;
    int b4 = (tid / 32) * 4, nl = (tid % 32) * 2;
    for (int kt = kbeg; kt < kend; kt += 32) {
        float4 a4 = *reinterpret_cast<const float4*>(A + (size_t)lb * lda + kt + lkq * 4);
        As[(lkq * 4 + 0) * 32 + lb] = a4.x; As[(lkq * 4 + 1) * 32 + lb] = a4.y;
        As[(lkq * 4 + 2) * 32 + lb] = a4.z; As[(lkq * 4 + 3) * 32 + lb] = a4.w;
        #pragma unroll
        for (int r = 0; r < 2; ++r) {
            int s = tid + r * 256;
            int n_l = s / 8, kq = s % 8;
            float4 w4 = *reinterpret_cast<const float4*>(W + (size_t)(n0 + n_l) * wstride + kt + kq * 4);
            Ws[n_l][kq * 4 + 0] = w4.x; Ws[n_l][kq * 4 + 1] = w4.y;
            Ws[n_l][kq * 4 + 2] = w4.z; Ws[n_l][kq * 4 + 3] = w4.w;
        }
        __syncthreads();
        #pragma unroll
        for (int k = 0; k < 32; ++k) {
            float4 av = *reinterpret_cast<const float4*>(&As[k * 32 + b4]);
            float w0 = Ws[nl][k], w1 = Ws[nl + 1][k];
            acc[0][0] += av.x * w0; acc[0][1] += av.x * w1;
            acc[1][0] += av.y * w0; acc[1][1] += av.y * w1;
            acc[2][0] += av.z * w0; acc[2][1] += av.z * w1;
            acc[3][0] += av.w * w0; acc[3][1] += av.w * w1;
        }
        __syncthreads();
    }
}

// ---------------- h0/c0 skinny GEMM, split-K=8 (grid 16 x 8) -> partials in spart ----------------
__global__ __launch_bounds__(256) void gemm_skinny_split(
    const float* __restrict__ A0, const float* __restrict__ W0a, const float* __restrict__ W0b,
    float* __restrict__ spart)
{
    __shared__ float As[1024];
    __shared__ float Ws[64][33];
    int n0 = blockIdx.x * 64;
    int ks = blockIdx.y;
    int tid = threadIdx.x;
    int lb = tid / 8, lkq = tid % 8;
    int b4 = (tid / 32) * 4, nl = (tid % 32) * 2;
    float acc[4][2] = {};
    for (int kt = ks * 256; kt < ks * 256 + 256; kt += 32) {
        float4 a4 = *reinterpret_cast<const float4*>(A0 + (size_t)lb * NE + kt + lkq * 4);
        As[(lkq * 4 + 0) * 32 + lb] = a4.x; As[(lkq * 4 + 1) * 32 + lb] = a4.y;
        As[(lkq * 4 + 2) * 32 + lb] = a4.z; As[(lkq * 4 + 3) * 32 + lb] = a4.w;
        #pragma unroll
        for (int r = 0; r < 2; ++r) {
            int s = tid + r * 256;
            int n_l = s / 8, kq = s % 8;
            int ng = n0 + n_l;
            const float* wrow = (ng < 512) ? (W0a + (size_t)ng * NE)
                                           : (W0b + (size_t)(ng - 512) * NE);
            float4 w4 = *reinterpret_cast<const float4*>(wrow + kt + kq * 4);
            Ws[n_l][kq * 4 + 0] = w4.x; Ws[n_l][kq * 4 + 1] = w4.y;
            Ws[n_l][kq * 4 + 2] = w4.z; Ws[n_l][kq * 4 + 3] = w4.w;
        }
        __syncthreads();
        #pragma unroll
        for (int k = 0; k < 32; ++k) {
            float4 av = *reinterpret_cast<const float4*>(&As[k * 32 + b4]);
            float w0 = Ws[nl][k], w1 = Ws[nl + 1][k];
            acc[0][0] += av.x * w0; acc[0][1] += av.x * w1;
            acc[1][0] += av.y * w0; acc[1][1] += av.y * w1;
            acc[2][0] += av.z * w0; acc[2][1] += av.z * w1;
            acc[3][0] += av.w * w0; acc[3][1] += av.w * w1;
        }
        __syncthreads();
    }
    float* Cp = spart + (size_t)ks * NB * 1024;
    #pragma unroll
    for (int j = 0; j < 2; ++j)
        #pragma unroll
        for (int i = 0; i < 4; ++i)
            Cp[(size_t)(b4 + i) * 1024 + n0 + nl + j] = acc[i][j];
}

// combine partials + bias -> hc (grid NB)
__global__ __launch_bounds__(256) void k_hc0(
    const float* __restrict__ spart, const float* __restrict__ ba, const float* __restrict__ bb,
    float* __restrict__ hc)
{
    int b = blockIdx.x;
    for (int ng = threadIdx.x; ng < 1024; ng += 256) {
        float s = (ng < 512) ? ba[ng] : bb[ng - 512];
        #pragma unroll
        for (int ks = 0; ks < 8; ++ks)
            s += spart[(size_t)ks * NB * 1024 + (size_t)b * 1024 + ng];
        hc[(size_t)b * 1024 + ng] = s;
    }
}

// ---------------- att1 GEMM (bf16 MFMA), fp32 A with inline cvt, XCD-swizzled (proven) ----------------
__global__ __launch_bounds__(256) void gemm_att1_mfma(
    const float* __restrict__ enc, const float* __restrict__ W_ea,
    const float* __restrict__ bias, unsigned short* __restrict__ att1B,
    const int* __restrict__ sind)
{
    int fid = blockIdx.x;
    int c = fid & 7, x = (fid >> 3) & 7, pg = fid >> 6;
    int p = pg * 8 + c;
    if (p >= 98) return;
    int bm0 = p * 64, bn0 = x * 64;
    __shared__ unsigned short As[64][40];
    __shared__ unsigned short Bs[64][40];
    int tid = threadIdx.x;
    int w = tid >> 6, lane = tid & 63;
    int srow = tid >> 2, schunk = (tid & 3) * 8;
    int mg = bm0 + srow;
    int bidx = mg / NP, pp = mg - bidx * NP;
    const float* arow = enc + ((size_t)sind[bidx] * NP + pp) * NE + schunk;
    const float* brow = W_ea + (size_t)(bn0 + srow) * NE + schunk;
    int frow = lane & 15, fk = (lane >> 4) * 8;
    f32x4 acc[4] = {};
    for (int kt = 0; kt < NE; kt += 32) {
        float4 a0 = *reinterpret_cast<const float4*>(arow + kt);
        float4 a1 = *reinterpret_cast<const float4*>(arow + kt + 4);
        float4 b0 = *reinterpret_cast<const float4*>(brow + kt);
        float4 b1 = *reinterpret_cast<const float4*>(brow + kt + 4);
        uint4 av, bv;
        av.x = f2b(a0.x) | ((unsigned)f2b(a0.y) << 16);
        av.y = f2b(a0.z) | ((unsigned)f2b(a0.w) << 16);
        av.z = f2b(a1.x) | ((unsigned)f2b(a1.y) << 16);
        av.w = f2b(a1.z) | ((unsigned)f2b(a1.w) << 16);
        bv.x = f2b(b0.x) | ((unsigned)f2b(b0.y) << 16);
        bv.y = f2b(b0.z) | ((unsigned)f2b(b0.w) << 16);
        bv.z = f2b(b1.x) | ((unsigned)f2b(b1.y) << 16);
        bv.w = f2b(b1.z) | ((unsigned)f2b(b1.w) << 16);
        *reinterpret_cast<uint4*>(&As[srow][schunk]) = av;
        *reinterpret_cast<uint4*>(&Bs[srow][schunk]) = bv;
        __syncthreads();
        short8 af = *reinterpret_cast<const short8*>(&As[w * 16 + frow][fk]);
        #pragma unroll
        for (int n = 0; n < 4; ++n) {
            short8 bf = *reinterpret_cast<const short8*>(&Bs[n * 16 + frow][fk]);
            acc[n] = __builtin_amdgcn_mfma_f32_16x16x32_bf16(af, bf, acc[n], 0, 0, 0);
        }
        __syncthreads();
    }
    int crow = bm0 + w * 16 + (lane >> 4) * 4;
    int ccol0 = lane & 15;
    #pragma unroll
    for (int n = 0; n < 4; ++n) {
        int col = bn0 + n * 16 + ccol0;
        float bb2 = bias[col];
        #pragma unroll
        for (int i = 0; i < 4; ++i)
            att1B[(size_t)(crow + i) * ND + col] = f2b(acc[n][i] + bb2);
    }
}

// ---------------- preds GEMM (bf16 MFMA): BM=128 BN=128, XCD-swizzled ----------------
// fid = ((g*5 + m)<<3) | c ; n = g*8+c (W-panel of 128), m = m-tile of 128 rows.
__global__ __launch_bounds__(256) void gemm_preds_mfma(
    const unsigned short* __restrict__ hseqB, const float* __restrict__ W_fc,
    const float* __restrict__ bias, float* __restrict__ out,
    const int* __restrict__ rowmap, const int* __restrict__ mpad)
{
    int fid = blockIdx.x;
    int c = fid & 7;
    int rem = fid >> 3;
    int m = rem % 5, g = rem / 5;
    int n = g * 8 + c;
    if (n >= 250) return;
    int bm0 = m * 128;
    if (bm0 >= mpad[0]) return;
    int bn0 = n * 128;
    __shared__ unsigned short As[128][40];
    __shared__ unsigned short Bs[128][40];
    int tid = threadIdx.x;
    int w = tid >> 6, lane = tid & 63;
    int srow = tid >> 1, shalf = (tid & 1) * 16;
    int rid = rowmap[bm0 + srow];
    const unsigned short* aptr = hseqB + (size_t)(rid < 0 ? 0 : rid) * ND + shalf;
    const float* bptr = W_fc + (size_t)(bn0 + srow) * ND + shalf;
    int frow = lane & 15, fk = (lane >> 4) * 8;
    f32x4 acc[2][8] = {};
    for (int kt = 0; kt < ND; kt += 32) {
        uint4 a0 = *reinterpret_cast<const uint4*>(aptr + kt);
        uint4 a1 = *reinterpret_cast<const uint4*>(aptr + kt + 8);
        float4 c0 = *reinterpret_cast<const float4*>(bptr + kt);
        float4 c1 = *reinterpret_cast<const float4*>(bptr + kt + 4);
        float4 c2 = *reinterpret_cast<const float4*>(bptr + kt + 8);
        float4 c3 = *reinterpret_cast<const float4*>(bptr + kt + 12);
        uint4 bv0, bv1;
        bv0.x = f2b(c0.x) | ((unsigned)f2b(c0.y) << 16);
        bv0.y = f2b(c0.z) | ((unsigned)f2b(c0.w) << 16);
        bv0.z = f2b(c1.x) | ((unsigned)f2b(c1.y) << 16);
        bv0.w = f2b(c1.z) | ((unsigned)f2b(c1.w) << 16);
        bv1.x = f2b(c2.x) | ((unsigned)f2b(c2.y) << 16);
        bv1.y = f2b(c2.z) | ((unsigned)f2b(c2.w) << 16);
        bv1.z = f2b(c3.x) | ((unsigned)f2b(c3.y) << 16);
        bv1.w = f2b(c3.z) | ((unsigned)f2b(c3.w) << 16);
        *reinterpret_cast<uint4*>(&As[srow][shalf]) = a0;
        *reinterpret_cast<uint4*>(&As[srow][shalf + 8]) = a1;
        *reinterpret_cast<uint4*>(&Bs[srow][shalf]) = bv0;
        *reinterpret_cast<uint4*>(&Bs[srow][shalf + 8]) = bv1;
        __syncthreads();
        #pragma unroll
        for (int h = 0; h < 2; ++h) {
            short8 af = *reinterpret_cast<const short8*>(&As[w * 32 + h * 16 + frow][fk]);
            #pragma unroll
            for (int nn = 0; nn < 8; ++nn) {
                short8 bf = *reinterpret_cast<const short8*>(&Bs[nn * 16 + frow][fk]);
                acc[h][nn] = __builtin_amdgcn_mfma_f32_16x16x32_bf16(af, bf, acc[h][nn], 0, 0, 0);
            }
        }
        __syncthreads();
    }
    int ccol0 = lane & 15;
    #pragma unroll
    for (int h = 0; h < 2; ++h) {
        int rl0 = w * 32 + h * 16 + (lane >> 4) * 4;
        #pragma unroll
        for (int i = 0; i < 4; ++i) {
            int rm = rowmap[bm0 + rl0 + i];
            if (rm < 0) continue;
            int t = rm / NB, b = rm % NB;
            float* orow = out + ((size_t)b * NT + t) * NV;
            #pragma unroll
            for (int nn = 0; nn < 8; ++nn) {
                int col = bn0 + nn * 16 + ccol0;
                orow[col] = acc[h][nn][i] + bias[col];
            }
        }
    }
}

// ---------------- k_phase1: attg (blocks 0..39) + eh gate-partials (blocks 40..103) ----------------
__global__ __launch_bounds__(256) void k_phase1(
    const float* __restrict__ hc, const float* __restrict__ W_da, const float* __restrict__ W_fb,
    const float* __restrict__ b_da, const float* __restrict__ b_fb,
    const float* __restrict__ embS, const float* __restrict__ W_ih, const float* __restrict__ W_hh,
    float* __restrict__ attg, float* __restrict__ gpart, int t)
{
    __shared__ float As[1024];
    __shared__ float Ws[64][33];
    int blk = blockIdx.x, tid = threadIdx.x;
    int b4 = (tid / 32) * 4, nl = (tid % 32) * 2;
    float acc[4][2] = {};
    if (blk < 40) {
        int n0 = blk * 64;
        int lb = tid / 8, lkq = tid % 8;
        for (int kt = 0; kt < 512; kt += 32) {
            float4 a4 = *reinterpret_cast<const float4*>(hc + (size_t)lb * 1024 + kt + lkq * 4);
            As[(lkq * 4 + 0) * 32 + lb] = a4.x; As[(lkq * 4 + 1) * 32 + lb] = a4.y;
            As[(lkq * 4 + 2) * 32 + lb] = a4.z; As[(lkq * 4 + 3) * 32 + lb] = a4.w;
            #pragma unroll
            for (int r = 0; r < 2; ++r) {
                int s = tid + r * 256;
                int n_l = s / 8, kq = s % 8;
                int ng = n0 + n_l;
                const float* wrow = (ng < 512) ? (W_da + (size_t)ng * 512)
                                               : (W_fb + (size_t)(ng - 512) * 512);
                float4 w4 = *reinterpret_cast<const float4*>(wrow + kt + kq * 4);
                Ws[n_l][kq * 4 + 0] = w4.x; Ws[n_l][kq * 4 + 1] = w4.y;
                Ws[n_l][kq * 4 + 2] = w4.z; Ws[n_l][kq * 4 + 3] = w4.w;
            }
            __syncthreads();
            #pragma unroll
            for (int k = 0; k < 32; ++k) {
                float4 av = *reinterpret_cast<const float4*>(&As[k * 32 + b4]);
                float w0 = Ws[nl][k], w1 = Ws[nl + 1][k];
                acc[0][0] += av.x * w0; acc[0][1] += av.x * w1;
                acc[1][0] += av.y * w0; acc[1][1] += av.y * w1;
                acc[2][0] += av.z * w0; acc[2][1] += av.z * w1;
                acc[3][0] += av.w * w0; acc[3][1] += av.w * w1;
            }
            __syncthreads();
        }
        #pragma unroll
        for (int j = 0; j < 2; ++j) {
            int ng = n0 + nl + j;
            float bias = (ng < 512) ? b_da[ng] : b_fb[ng - 512];
            #pragma unroll
            for (int i = 0; i < 4; ++i)
                attg[(size_t)(b4 + i) * 2560 + ng] = acc[i][j] + bias;
        }
    } else if (blk < 72) {
        int nt = blk - 40, n0 = nt * 64;
        tile_body_uniW(embS + (size_t)t * NB * ND, ND, W_ih, 2560, n0, 0, 512, As, Ws, acc, tid);
        float* Cp = gpart + (size_t)4 * NB * 2048;
        #pragma unroll
        for (int j = 0; j < 2; ++j)
            #pragma unroll
            for (int i = 0; i < 4; ++i)
                Cp[(size_t)(b4 + i) * 2048 + n0 + nl + j] = acc[i][j];
    } else {
        int nt = blk - 72, n0 = nt * 64;
        tile_body_uniW(hc, 1024, W_hh, 512, n0, 0, 512, As, Ws, acc, tid);
        float* Cp = gpart + (size_t)5 * NB * 2048;
        #pragma unroll
        for (int j = 0; j < 2; ++j)
            #pragma unroll
            for (int i = 0; i < 4; ++i)
                Cp[(size_t)(b4 + i) * 2048 + n0 + nl + j] = acc[i][j];
    }
}

// ---------------- k_e: e scores from bf16 att1 (grid 7 x 32) ----------------
__global__ __launch_bounds__(256) void k_e(
    const unsigned short* __restrict__ att1B, const float* __restrict__ attg,
    const float* __restrict__ w_fa, const float* __restrict__ b_fa,
    float* __restrict__ e)
{
    __shared__ float att2s[ND];
    __shared__ float wfas[ND];
    int b = blockIdx.y, tid = threadIdx.x;
    const float* ag = attg + (size_t)b * 2560;
    for (int d = tid; d < ND; d += 256) { att2s[d] = ag[d]; wfas[d] = w_fa[d]; }
    __syncthreads();
    int w = tid >> 6, lane = tid & 63;
    int p0 = blockIdx.x * 28;
    const unsigned short* a1 = att1B + ((size_t)b * NP + p0) * ND;
    #pragma unroll
    for (int i = 0; i < 7; ++i) {
        int p = w + 4 * i;
        const unsigned short* row = a1 + (size_t)p * ND;
        float s = 0.f;
        #pragma unroll
        for (int j = 0; j < 2; ++j) {
            int d = j * 256 + lane * 4;
            uint2 u = *reinterpret_cast<const uint2*>(row + d);   // 4 bf16
            float v0 = b2f_lo(u.x), v1 = b2f_hi(u.x);
            float v2 = b2f_lo(u.y), v3 = b2f_hi(u.y);
            float4 a2 = *reinterpret_cast<const float4*>(&att2s[d]);
            float4 wf = *reinterpret_cast<const float4*>(&wfas[d]);
            s += fmaxf(v0 + a2.x, 0.f) * wf.x + fmaxf(v1 + a2.y, 0.f) * wf.y
               + fmaxf(v2 + a2.z, 0.f) * wf.z + fmaxf(v3 + a2.w, 0.f) * wf.w;
        }
        for (int off = 32; off > 0; off >>= 1) s += __shfl_down(s, off);
        if (lane == 0) e[(size_t)b * NP + p0 + p] = s + b_fa[0];
    }
}

// ---------------- k_awe: softmax + awe (bf16 enc) + gate -> xh gawe; alpha (grid 8 x 32) ----------------
__global__ __launch_bounds__(256) void k_awe(
    const unsigned short* __restrict__ encB, const int* __restrict__ dlens,
    const float* __restrict__ e, const float* __restrict__ attg,
    float* __restrict__ xh, float* __restrict__ out_alpha, int t)
{
    __shared__ float es[256];
    __shared__ float red[256];
    int kc = blockIdx.x, b = blockIdx.y, tid = threadIdx.x;
    float ev = -1e30f;
    if (tid < NP) { float v = e[(size_t)b * NP + tid]; es[tid] = v; ev = v; }
    red[tid] = ev; __syncthreads();
    for (int s2 = 128; s2 > 0; s2 >>= 1) { if (tid < s2) red[tid] = fmaxf(red[tid], red[tid + s2]); __syncthreads(); }
    float m = red[0]; __syncthreads();
    float xe = (tid < NP) ? expf(es[tid] - m) : 0.f;
    red[tid] = xe; __syncthreads();
    for (int s2 = 128; s2 > 0; s2 >>= 1) { if (tid < s2) red[tid] += red[tid + s2]; __syncthreads(); }
    float inv = 1.0f / red[0];
    __syncthreads();
    es[tid] = xe * inv;
    __syncthreads();

    int k = kc * 256 + tid;
    const unsigned short* ec = encB + (size_t)b * NP * NE + k;
    float s0 = 0.f, s1 = 0.f, s2v = 0.f, s3 = 0.f;
    #pragma unroll 4
    for (int p = 0; p < NP; p += 4) {
        s0 += es[p + 0] * b2f(ec[(size_t)(p + 0) * NE]);
        s1 += es[p + 1] * b2f(ec[(size_t)(p + 1) * NE]);
        s2v += es[p + 2] * b2f(ec[(size_t)(p + 2) * NE]);
        s3 += es[p + 3] * b2f(ec[(size_t)(p + 3) * NE]);
    }
    float awe = (s0 + s1) + (s2v + s3);
    float gp = attg[(size_t)b * 2560 + 512 + k];      // includes b_fb
    float gate = 1.f / (1.f + expf(-gp));
    xh[(size_t)b * 3072 + 512 + k] = gate * awe;
    if (kc == 0 && tid < NP) {
        bool live = (t < dlens[b]);
        out_alpha[((size_t)b * NT + t) * NP + tid] = live ? es[tid] : 0.f;
    }
}

// ---------------- k_gatescell: full-K gawe GEMM (gathered 4-quadrant W rows) + fused cell ----------------
// grid 128: block dc owns d = dc*4 .. dc*4+3 for ALL 4 gate quadrants (16 W_ih rows).
// gates = gawe@W_ih[:,512:2560]^T (K=2048, complete in-block) + gpart slices 4(emb),5(h) + biases.
__global__ __launch_bounds__(256) void k_gatescell(
    const float* __restrict__ xh, const float* __restrict__ W_ih,
    const float* __restrict__ gpart, const int* __restrict__ dlens,
    const float* __restrict__ b_ih, const float* __restrict__ b_hh,
    float* __restrict__ hc, unsigned short* __restrict__ hseqB, int t)
{
    __shared__ float As[1024];      // [32 k][32 b]
    __shared__ float Ws[16][33];    // [16 gathered rows][32 k]
    __shared__ float Gs[512];       // [16 r][32 b]
    int dc = blockIdx.x, tid = threadIdx.x;
    int lb = tid / 8, lkq = tid % 8;
    int wr = tid >> 4, wk = (tid & 15) * 2;
    int grow = (wr >> 2) * 512 + dc * 4 + (wr & 3);
    const float* wrow = W_ih + (size_t)grow * 2560 + 512;
    int r = tid & 15, bp = tid >> 4;
    int b0 = bp * 2;
    float acc0 = 0.f, acc1 = 0.f;
    for (int kt = 0; kt < 2048; kt += 32) {
        float4 a4 = *reinterpret_cast<const float4*>(xh + (size_t)lb * 3072 + 512 + kt + lkq * 4);
        As[(lkq * 4 + 0) * 32 + lb] = a4.x; As[(lkq * 4 + 1) * 32 + lb] = a4.y;
        As[(lkq * 4 + 2) * 32 + lb] = a4.z; As[(lkq * 4 + 3) * 32 + lb] = a4.w;
        float2 w2 = *reinterpret_cast<const float2*>(wrow + kt + wk);
        Ws[wr][wk] = w2.x; Ws[wr][wk + 1] = w2.y;
        __syncthreads();
        #pragma unroll
        for (int k = 0; k < 32; ++k) {
            float wv = Ws[r][k];
            float2 av = *reinterpret_cast<const float2*>(&As[k * 32 + b0]);
            acc0 += av.x * wv;
            acc1 += av.y * wv;
        }
        __syncthreads();
    }
    Gs[r * 32 + b0] = acc0;
    Gs[r * 32 + b0 + 1] = acc1;
    __syncthreads();
    if (tid < 128) {
        int d_l = tid & 3, b = tid >> 2;
        int d = dc * 4 + d_l;
        const float* gp4 = gpart + ((size_t)4 * NB + b) * 2048;
        const float* gp5 = gpart + ((size_t)5 * NB + b) * 2048;
        float g[4];
        #pragma unroll
        for (int q = 0; q < 4; ++q) {
            int n = q * 512 + d;
            g[q] = Gs[(q * 4 + d_l) * 32 + b] + gp4[n] + gp5[n] + b_ih[n] + b_hh[n];
        }
        float ig = 1.f / (1.f + expf(-g[0]));
        float fg = 1.f / (1.f + expf(-g[1]));
        float gt = tanhf(g[2]);
        float og = 1.f / (1.f + expf(-g[3]));
        float c_old = hc[(size_t)b * 1024 + 512 + d];
        float c_new = fg * c_old + ig * gt;
        float h_new = og * tanhf(c_new);
        hseqB[((size_t)t * NB + b) * ND + d] = f2b(h_new);
        if (t < dlens[b]) {
            hc[(size_t)b * 1024 + d] = h_new;
            hc[(size_t)b * 1024 + 512 + d] = c_new;
        }
    }
}

// ---------------- launcher ----------------
extern "C" void kernel_launch(void* const* d_in, const int* in_sizes, int n_in,
                              void* d_out, int out_size, void* d_ws, size_t ws_size,
                              hipStream_t stream)
{
    const float* enc   = (const float*)d_in[0];
    const int*   caps  = (const int*)d_in[1];
    const int*   clens = (const int*)d_in[2];
    const float* emb_W = (const float*)d_in[3];
    const float* W_ea  = (const float*)d_in[4];
    const float* b_ea  = (const float*)d_in[5];
    const float* W_da  = (const float*)d_in[6];
    const float* b_da  = (const float*)d_in[7];
    const float* w_fa  = (const float*)d_in[8];
    const float* b_fa  = (const float*)d_in[9];
    const float* W_ih  = (const float*)d_in[10];
    const float* b_ih  = (const float*)d_in[11];
    const float* W_hh  = (const float*)d_in[12];
    const float* b_hh  = (const float*)d_in[13];
    const float* W_h0  = (const float*)d_in[14];
    const float* b_h0  = (const float*)d_in[15];
    const float* W_c0  = (const float*)d_in[16];
    const float* b_c0  = (const float*)d_in[17];
    const float* W_fb  = (const float*)d_in[18];
    const float* b_fb  = (const float*)d_in[19];
    const float* W_fc  = (const float*)d_in[20];
    const float* b_fc  = (const float*)d_in[21];

    float* out = (float*)d_out;
    float* out_alpha = out + (size_t)NB * NT * NV;

    int* iws    = (int*)d_ws;
    int* sind   = iws;
    int* dlens  = iws + 32;
    int* rowmap = iws + 64;
    int* mpad   = iws + 704;
    float* base = (float*)d_ws + 1024;
    float* mean_enc = base;                         // 65536
    float* hc    = mean_enc + NB * NE;              // 32768
    float* attg  = hc + NB * 1024;                  // 81920
    float* xh    = attg + NB * 2560;                // 98304
    float* e     = xh + NB * 3072;                  // 6272
    float* embS  = e + NB * NP;                     // 327680
    float* gpart = embS + (size_t)NT * NB * ND;     // 6*32*2048 = 393216 (spart at setup fits)
    unsigned short* att1B = (unsigned short*)(gpart + 6 * NB * 2048);   // 6272*512 bf16
    unsigned short* hseqB = att1B + (size_t)NB * NP * ND;               // 640*512 bf16
    unsigned short* encB  = hseqB + (size_t)NT * NB * ND;               // 32*196*2048 bf16

    k_sort<<<1, 64, 0, stream>>>(clens, sind, dlens, rowmap, mpad);
    k_zero<<<NB * NT, 256, 0, stream>>>(dlens, out);
    k_conv_enc<<<dim3(NB * NP * NE / 2048), 256, 0, stream>>>(enc, sind, encB);
    k_emb<<<dim3(NT, NB), 256, 0, stream>>>(caps, sind, emb_W, embS);
    k_mean<<<dim3(NE / 256, NB), 256, 0, stream>>>(enc, sind, mean_enc);
    gemm_skinny_split<<<dim3(16, 8), 256, 0, stream>>>(mean_enc, W_h0, W_c0, gpart);
    k_hc0<<<dim3(NB), 256, 0, stream>>>(gpart, b_h0, b_c0, hc);
    gemm_att1_mfma<<<dim3(832), 256, 0, stream>>>(enc, W_ea, b_ea, att1B, sind);

    for (int t = 0; t < NT; ++t) {
        k_phase1<<<dim3(104), 256, 0, stream>>>(hc, W_da, W_fb, b_da, b_fb,
                                                embS, W_ih, W_hh, attg, gpart, t);
        k_e<<<dim3(7, NB), 256, 0, stream>>>(att1B, attg, w_fa, b_fa, e);
        k_awe<<<dim3(8, NB), 256, 0, stream>>>(encB, dlens, e, attg, xh, out_alpha, t);
        k_gatescell<<<dim3(128), 256, 0, stream>>>(xh, W_ih, gpart, dlens,
                                                   b_ih, b_hh, hc, hseqB, t);
    }

    gemm_preds_mfma<<<dim3(1280), 256, 0, stream>>>(hseqB, W_fc, b_fc, out, rowmap, mpad);
}

// Round 19
// 1580.939 us; speedup vs baseline: 1.4119x; 1.4119x over previous
//
#include <hip/hip_runtime.h>
#include <hip/hip_bf16.h>
#include <cstddef>

#define NB 32      // batch
#define NP 196     // pixels
#define NE 2048    // encoder dim
#define ND 512     // decoder/att/emb dim
#define NV 32000   // vocab
#define NL 21
#define NT 20      // decode steps

typedef __attribute__((ext_vector_type(8))) short short8;   // 8 bf16 (4 VGPRs)
typedef __attribute__((ext_vector_type(4))) float f32x4;

__device__ __forceinline__ unsigned short f2b(float f) {
    __hip_bfloat16 h = __float2bfloat16(f);      // RNE
    return *reinterpret_cast<unsigned short*>(&h);
}
__device__ __forceinline__ float b2f(unsigned short u) {
    union { unsigned int i; float f; } v; v.i = (unsigned)u << 16; return v.f;
}
__device__ __forceinline__ float b2f_lo(unsigned int u) {
    union { unsigned int i; float f; } v; v.i = u << 16; return v.f;
}
__device__ __forceinline__ float b2f_hi(unsigned int u) {
    union { unsigned int i; float f; } v; v.i = u & 0xffff0000u; return v.f;
}

// ---------------- setup ----------------

__global__ void k_sort(const int* __restrict__ lens, int* __restrict__ sind, int* __restrict__ dlens,
                       int* __restrict__ rowmap, int* __restrict__ mpad)
{
    int i = threadIdx.x;
    if (i < NB) {
        int li = lens[i];
        int r = 0;
        for (int j = 0; j < NB; ++j) {
            int lj = lens[j];
            if (lj > li || (lj == li && j < i)) ++r;
        }
        sind[r] = i;
        dlens[r] = li - 1;
    }
    __syncthreads();
    if (i == 0) {
        int c = 0;
        for (int t = 0; t < NT; ++t)
            for (int b = 0; b < NB; ++b)
                if (t < dlens[b]) rowmap[c++] = t * NB + b;
        int pad = (c + 63) & ~63;
        for (int r = c; r < pad; ++r) rowmap[r] = -1;
        mpad[0] = pad;
    }
}

// enc (sorted) -> bf16 copy (grid 6272) — consumed by k_awe only
__global__ __launch_bounds__(256) void k_conv_enc(
    const float* __restrict__ enc, const int* __restrict__ sind,
    unsigned short* __restrict__ encB)
{
    int idx = (blockIdx.x * 256 + threadIdx.x) * 8;
    int b = idx / (NP * NE), rem = idx - b * (NP * NE);
    const float* src = enc + (size_t)sind[b] * NP * NE + rem;
    float4 a = *reinterpret_cast<const float4*>(src);
    float4 c = *reinterpret_cast<const float4*>(src + 4);
    uint4 o;
    o.x = f2b(a.x) | ((unsigned)f2b(a.y) << 16);
    o.y = f2b(a.z) | ((unsigned)f2b(a.w) << 16);
    o.z = f2b(c.x) | ((unsigned)f2b(c.y) << 16);
    o.w = f2b(c.z) | ((unsigned)f2b(c.w) << 16);
    *reinterpret_cast<uint4*>(encB + idx) = o;
}

// embS[t][b][512] = emb_W[caps[sind[b]][t]]   (grid (NT, NB))
__global__ __launch_bounds__(256) void k_emb(
    const int* __restrict__ caps, const int* __restrict__ sind,
    const float* __restrict__ emb_W, float* __restrict__ embS)
{
    int t = blockIdx.x, b = blockIdx.y;
    const float* src = emb_W + (size_t)caps[sind[b] * NL + t] * ND;
    float* dst = embS + ((size_t)t * NB + b) * ND;
    int i = threadIdx.x * 2;
    *reinterpret_cast<float2*>(dst + i) = *reinterpret_cast<const float2*>(src + i);
}

__global__ __launch_bounds__(256) void k_mean(const float* __restrict__ enc, const int* __restrict__ sind,
                                              float* __restrict__ mean_enc)
{
    int b = blockIdx.y;
    int k = blockIdx.x * 256 + threadIdx.x;
    const float* e = enc + (size_t)sind[b] * NP * NE + k;
    float s0 = 0.f, s1 = 0.f, s2 = 0.f, s3 = 0.f;
    for (int p = 0; p < NP; p += 4) {
        s0 += e[(size_t)(p + 0) * NE];
        s1 += e[(size_t)(p + 1) * NE];
        s2 += e[(size_t)(p + 2) * NE];
        s3 += e[(size_t)(p + 3) * NE];
    }
    mean_enc[(size_t)b * NE + k] = (s0 + s1 + s2 + s3) * (1.0f / NP);
}

__global__ __launch_bounds__(256) void k_zero(const int* __restrict__ dlens, float* __restrict__ out)
{
    int b = blockIdx.x / NT, t = blockIdx.x % NT;
    if (t < dlens[b]) return;
    float4 z = {0.f, 0.f, 0.f, 0.f};
    float4* row = (float4*)(out + ((size_t)b * NT + t) * NV);
    for (int i = threadIdx.x; i < NV / 4; i += 256) row[i] = z;
}

// ---------------- shared tile body: C_part[32][64] = A[32][K] @ W^T (uniform W) ----------------
__device__ __forceinline__ void tile_body_uniW(
    const float* __restrict__ A, int lda, const float* __restrict__ W, int wstride,
    int n0, int kbeg, int kend, float* As, float (*Ws)[33], float acc[4][2],
    int tid)
{
    int lb = tid / 8, lkq = tid % 8;
    int b4 = (tid / 32) * 4, nl = (tid % 32) * 2;
    for (int kt = kbeg; kt < kend; kt += 32) {
        float4 a4 = *reinterpret_cast<const float4*>(A + (size_t)lb * lda + kt + lkq * 4);
        As[(lkq * 4 + 0) * 32 + lb] = a4.x; As[(lkq * 4 + 1) * 32 + lb] = a4.y;
        As[(lkq * 4 + 2) * 32 + lb] = a4.z; As[(lkq * 4 + 3) * 32 + lb] = a4.w;
        #pragma unroll
        for (int r = 0; r < 2; ++r) {
            int s = tid + r * 256;
            int n_l = s / 8, kq = s % 8;
            float4 w4 = *reinterpret_cast<const float4*>(W + (size_t)(n0 + n_l) * wstride + kt + kq * 4);
            Ws[n_l][kq * 4 + 0] = w4.x; Ws[n_l][kq * 4 + 1] = w4.y;
            Ws[n_l][kq * 4 + 2] = w4.z; Ws[n_l][kq * 4 + 3] = w4.w;
        }
        __syncthreads();
        #pragma unroll
        for (int k = 0; k < 32; ++k) {
            float4 av = *reinterpret_cast<const float4*>(&As[k * 32 + b4]);
            float w0 = Ws[nl][k], w1 = Ws[nl + 1][k];
            acc[0][0] += av.x * w0; acc[0][1] += av.x * w1;
            acc[1][0] += av.y * w0; acc[1][1] += av.y * w1;
            acc[2][0] += av.z * w0; acc[2][1] += av.z * w1;
            acc[3][0] += av.w * w0; acc[3][1] += av.w * w1;
        }
        __syncthreads();
    }
}

// ---------------- h0/c0 skinny GEMM, split-K=8 (grid 16 x 8) -> partials in spart ----------------
__global__ __launch_bounds__(256) void gemm_skinny_split(
    const float* __restrict__ A0, const float* __restrict__ W0a, const float* __restrict__ W0b,
    float* __restrict__ spart)
{
    __shared__ float As[1024];
    __shared__ float Ws[64][33];
    int n0 = blockIdx.x * 64;
    int ks = blockIdx.y;
    int tid = threadIdx.x;
    int lb = tid / 8, lkq = tid % 8;
    int b4 = (tid / 32) * 4, nl = (tid % 32) * 2;
    float acc[4][2] = {};
    for (int kt = ks * 256; kt < ks * 256 + 256; kt += 32) {
        float4 a4 = *reinterpret_cast<const float4*>(A0 + (size_t)lb * NE + kt + lkq * 4);
        As[(lkq * 4 + 0) * 32 + lb] = a4.x; As[(lkq * 4 + 1) * 32 + lb] = a4.y;
        As[(lkq * 4 + 2) * 32 + lb] = a4.z; As[(lkq * 4 + 3) * 32 + lb] = a4.w;
        #pragma unroll
        for (int r = 0; r < 2; ++r) {
            int s = tid + r * 256;
            int n_l = s / 8, kq = s % 8;
            int ng = n0 + n_l;
            const float* wrow = (ng < 512) ? (W0a + (size_t)ng * NE)
                                           : (W0b + (size_t)(ng - 512) * NE);
            float4 w4 = *reinterpret_cast<const float4*>(wrow + kt + kq * 4);
            Ws[n_l][kq * 4 + 0] = w4.x; Ws[n_l][kq * 4 + 1] = w4.y;
            Ws[n_l][kq * 4 + 2] = w4.z; Ws[n_l][kq * 4 + 3] = w4.w;
        }
        __syncthreads();
        #pragma unroll
        for (int k = 0; k < 32; ++k) {
            float4 av = *reinterpret_cast<const float4*>(&As[k * 32 + b4]);
            float w0 = Ws[nl][k], w1 = Ws[nl + 1][k];
            acc[0][0] += av.x * w0; acc[0][1] += av.x * w1;
            acc[1][0] += av.y * w0; acc[1][1] += av.y * w1;
            acc[2][0] += av.z * w0; acc[2][1] += av.z * w1;
            acc[3][0] += av.w * w0; acc[3][1] += av.w * w1;
        }
        __syncthreads();
    }
    float* Cp = spart + (size_t)ks * NB * 1024;
    #pragma unroll
    for (int j = 0; j < 2; ++j)
        #pragma unroll
        for (int i = 0; i < 4; ++i)
            Cp[(size_t)(b4 + i) * 1024 + n0 + nl + j] = acc[i][j];
}

// combine partials + bias -> hc (grid NB)
__global__ __launch_bounds__(256) void k_hc0(
    const float* __restrict__ spart, const float* __restrict__ ba, const float* __restrict__ bb,
    float* __restrict__ hc)
{
    int b = blockIdx.x;
    for (int ng = threadIdx.x; ng < 1024; ng += 256) {
        float s = (ng < 512) ? ba[ng] : bb[ng - 512];
        #pragma unroll
        for (int ks = 0; ks < 8; ++ks)
            s += spart[(size_t)ks * NB * 1024 + (size_t)b * 1024 + ng];
        hc[(size_t)b * 1024 + ng] = s;
    }
}

// ---------------- att1 GEMM (bf16 MFMA), fp32 A with inline cvt, XCD-swizzled (proven) ----------------
__global__ __launch_bounds__(256) void gemm_att1_mfma(
    const float* __restrict__ enc, const float* __restrict__ W_ea,
    const float* __restrict__ bias, unsigned short* __restrict__ att1B,
    const int* __restrict__ sind)
{
    int fid = blockIdx.x;
    int c = fid & 7, x = (fid >> 3) & 7, pg = fid >> 6;
    int p = pg * 8 + c;
    if (p >= 98) return;
    int bm0 = p * 64, bn0 = x * 64;
    __shared__ unsigned short As[64][40];
    __shared__ unsigned short Bs[64][40];
    int tid = threadIdx.x;
    int w = tid >> 6, lane = tid & 63;
    int srow = tid >> 2, schunk = (tid & 3) * 8;
    int mg = bm0 + srow;
    int bidx = mg / NP, pp = mg - bidx * NP;
    const float* arow = enc + ((size_t)sind[bidx] * NP + pp) * NE + schunk;
    const float* brow = W_ea + (size_t)(bn0 + srow) * NE + schunk;
    int frow = lane & 15, fk = (lane >> 4) * 8;
    f32x4 acc[4] = {};
    for (int kt = 0; kt < NE; kt += 32) {
        float4 a0 = *reinterpret_cast<const float4*>(arow + kt);
        float4 a1 = *reinterpret_cast<const float4*>(arow + kt + 4);
        float4 b0 = *reinterpret_cast<const float4*>(brow + kt);
        float4 b1 = *reinterpret_cast<const float4*>(brow + kt + 4);
        uint4 av, bv;
        av.x = f2b(a0.x) | ((unsigned)f2b(a0.y) << 16);
        av.y = f2b(a0.z) | ((unsigned)f2b(a0.w) << 16);
        av.z = f2b(a1.x) | ((unsigned)f2b(a1.y) << 16);
        av.w = f2b(a1.z) | ((unsigned)f2b(a1.w) << 16);
        bv.x = f2b(b0.x) | ((unsigned)f2b(b0.y) << 16);
        bv.y = f2b(b0.z) | ((unsigned)f2b(b0.w) << 16);
        bv.z = f2b(b1.x) | ((unsigned)f2b(b1.y) << 16);
        bv.w = f2b(b1.z) | ((unsigned)f2b(b1.w) << 16);
        *reinterpret_cast<uint4*>(&As[srow][schunk]) = av;
        *reinterpret_cast<uint4*>(&Bs[srow][schunk]) = bv;
        __syncthreads();
        short8 af = *reinterpret_cast<const short8*>(&As[w * 16 + frow][fk]);
        #pragma unroll
        for (int n = 0; n < 4; ++n) {
            short8 bf = *reinterpret_cast<const short8*>(&Bs[n * 16 + frow][fk]);
            acc[n] = __builtin_amdgcn_mfma_f32_16x16x32_bf16(af, bf, acc[n], 0, 0, 0);
        }
        __syncthreads();
    }
    int crow = bm0 + w * 16 + (lane >> 4) * 4;
    int ccol0 = lane & 15;
    #pragma unroll
    for (int n = 0; n < 4; ++n) {
        int col = bn0 + n * 16 + ccol0;
        float bb2 = bias[col];
        #pragma unroll
        for (int i = 0; i < 4; ++i)
            att1B[(size_t)(crow + i) * ND + col] = f2b(acc[n][i] + bb2);
    }
}

// ---------------- preds GEMM (bf16 MFMA): BM=64 BN=128, XCD-swizzled (R17-proven) ----------------
__global__ __launch_bounds__(256) void gemm_preds_mfma(
    const unsigned short* __restrict__ hseqB, const float* __restrict__ W_fc,
    const float* __restrict__ bias, float* __restrict__ out,
    const int* __restrict__ rowmap, const int* __restrict__ mpad)
{
    int fid = blockIdx.x;
    int c = fid & 7;
    int rem = fid >> 3;
    int m = rem % 10, g = rem / 10;
    int n = g * 8 + c;
    if (n >= 250) return;
    int bm0 = m * 64;
    if (bm0 >= mpad[0]) return;
    int bn0 = n * 128;
    __shared__ unsigned short As[64][40];
    __shared__ unsigned short Bs[128][40];
    int tid = threadIdx.x;
    int w = tid >> 6, lane = tid & 63;
    int srow = tid >> 2, schunk = (tid & 3) * 8;
    int rid = rowmap[bm0 + srow];
    const unsigned short* aptr = hseqB + (size_t)(rid < 0 ? 0 : rid) * ND + schunk;
    const float* bptr0 = W_fc + (size_t)(bn0 + srow) * ND + schunk;
    const float* bptr1 = W_fc + (size_t)(bn0 + 64 + srow) * ND + schunk;
    int frow = lane & 15, fk = (lane >> 4) * 8;
    f32x4 acc[8] = {};
    for (int kt = 0; kt < ND; kt += 32) {
        uint4 av = *reinterpret_cast<const uint4*>(aptr + kt);
        float4 c0 = *reinterpret_cast<const float4*>(bptr0 + kt);
        float4 c1 = *reinterpret_cast<const float4*>(bptr0 + kt + 4);
        float4 d0 = *reinterpret_cast<const float4*>(bptr1 + kt);
        float4 d1 = *reinterpret_cast<const float4*>(bptr1 + kt + 4);
        uint4 bv0, bv1;
        bv0.x = f2b(c0.x) | ((unsigned)f2b(c0.y) << 16);
        bv0.y = f2b(c0.z) | ((unsigned)f2b(c0.w) << 16);
        bv0.z = f2b(c1.x) | ((unsigned)f2b(c1.y) << 16);
        bv0.w = f2b(c1.z) | ((unsigned)f2b(c1.w) << 16);
        bv1.x = f2b(d0.x) | ((unsigned)f2b(d0.y) << 16);
        bv1.y = f2b(d0.z) | ((unsigned)f2b(d0.w) << 16);
        bv1.z = f2b(d1.x) | ((unsigned)f2b(d1.y) << 16);
        bv1.w = f2b(d1.z) | ((unsigned)f2b(d1.w) << 16);
        *reinterpret_cast<uint4*>(&As[srow][schunk]) = av;
        *reinterpret_cast<uint4*>(&Bs[srow][schunk]) = bv0;
        *reinterpret_cast<uint4*>(&Bs[64 + srow][schunk]) = bv1;
        __syncthreads();
        short8 af = *reinterpret_cast<const short8*>(&As[w * 16 + frow][fk]);
        #pragma unroll
        for (int nn = 0; nn < 8; ++nn) {
            short8 bf = *reinterpret_cast<const short8*>(&Bs[nn * 16 + frow][fk]);
            acc[nn] = __builtin_amdgcn_mfma_f32_16x16x32_bf16(af, bf, acc[nn], 0, 0, 0);
        }
        __syncthreads();
    }
    int rl0 = w * 16 + (lane >> 4) * 4;
    int ccol0 = lane & 15;
    #pragma unroll
    for (int i = 0; i < 4; ++i) {
        int rm = rowmap[bm0 + rl0 + i];
        if (rm < 0) continue;
        int t = rm / NB, b = rm % NB;
        float* orow = out + ((size_t)b * NT + t) * NV;
        #pragma unroll
        for (int nn = 0; nn < 8; ++nn) {
            int col = bn0 + nn * 16 + ccol0;
            orow[col] = acc[nn][i] + bias[col];
        }
    }
}

// ---------------- k_phase1: attg (blocks 0..39) + eh gate-partials (blocks 40..103) ----------------
__global__ __launch_bounds__(256) void k_phase1(
    const float* __restrict__ hc, const float* __restrict__ W_da, const float* __restrict__ W_fb,
    const float* __restrict__ b_da, const float* __restrict__ b_fb,
    const float* __restrict__ embS, const float* __restrict__ W_ih, const float* __restrict__ W_hh,
    float* __restrict__ attg, float* __restrict__ gpart, int t)
{
    __shared__ float As[1024];
    __shared__ float Ws[64][33];
    int blk = blockIdx.x, tid = threadIdx.x;
    int b4 = (tid / 32) * 4, nl = (tid % 32) * 2;
    float acc[4][2] = {};
    if (blk < 40) {
        int n0 = blk * 64;
        int lb = tid / 8, lkq = tid % 8;
        for (int kt = 0; kt < 512; kt += 32) {
            float4 a4 = *reinterpret_cast<const float4*>(hc + (size_t)lb * 1024 + kt + lkq * 4);
            As[(lkq * 4 + 0) * 32 + lb] = a4.x; As[(lkq * 4 + 1) * 32 + lb] = a4.y;
            As[(lkq * 4 + 2) * 32 + lb] = a4.z; As[(lkq * 4 + 3) * 32 + lb] = a4.w;
            #pragma unroll
            for (int r = 0; r < 2; ++r) {
                int s = tid + r * 256;
                int n_l = s / 8, kq = s % 8;
                int ng = n0 + n_l;
                const float* wrow = (ng < 512) ? (W_da + (size_t)ng * 512)
                                               : (W_fb + (size_t)(ng - 512) * 512);
                float4 w4 = *reinterpret_cast<const float4*>(wrow + kt + kq * 4);
                Ws[n_l][kq * 4 + 0] = w4.x; Ws[n_l][kq * 4 + 1] = w4.y;
                Ws[n_l][kq * 4 + 2] = w4.z; Ws[n_l][kq * 4 + 3] = w4.w;
            }
            __syncthreads();
            #pragma unroll
            for (int k = 0; k < 32; ++k) {
                float4 av = *reinterpret_cast<const float4*>(&As[k * 32 + b4]);
                float w0 = Ws[nl][k], w1 = Ws[nl + 1][k];
                acc[0][0] += av.x * w0; acc[0][1] += av.x * w1;
                acc[1][0] += av.y * w0; acc[1][1] += av.y * w1;
                acc[2][0] += av.z * w0; acc[2][1] += av.z * w1;
                acc[3][0] += av.w * w0; acc[3][1] += av.w * w1;
            }
            __syncthreads();
        }
        #pragma unroll
        for (int j = 0; j < 2; ++j) {
            int ng = n0 + nl + j;
            float bias = (ng < 512) ? b_da[ng] : b_fb[ng - 512];
            #pragma unroll
            for (int i = 0; i < 4; ++i)
                attg[(size_t)(b4 + i) * 2560 + ng] = acc[i][j] + bias;
        }
    } else if (blk < 72) {
        int nt = blk - 40, n0 = nt * 64;
        tile_body_uniW(embS + (size_t)t * NB * ND, ND, W_ih, 2560, n0, 0, 512, As, Ws, acc, tid);
        float* Cp = gpart + (size_t)4 * NB * 2048;
        #pragma unroll
        for (int j = 0; j < 2; ++j)
            #pragma unroll
            for (int i = 0; i < 4; ++i)
                Cp[(size_t)(b4 + i) * 2048 + n0 + nl + j] = acc[i][j];
    } else {
        int nt = blk - 72, n0 = nt * 64;
        tile_body_uniW(hc, 1024, W_hh, 512, n0, 0, 512, As, Ws, acc, tid);
        float* Cp = gpart + (size_t)5 * NB * 2048;
        #pragma unroll
        for (int j = 0; j < 2; ++j)
            #pragma unroll
            for (int i = 0; i < 4; ++i)
                Cp[(size_t)(b4 + i) * 2048 + n0 + nl + j] = acc[i][j];
    }
}

// ---------------- k_e: e scores from bf16 att1 (grid 7 x 32) ----------------
__global__ __launch_bounds__(256) void k_e(
    const unsigned short* __restrict__ att1B, const float* __restrict__ attg,
    const float* __restrict__ w_fa, const float* __restrict__ b_fa,
    float* __restrict__ e)
{
    __shared__ float att2s[ND];
    __shared__ float wfas[ND];
    int b = blockIdx.y, tid = threadIdx.x;
    const float* ag = attg + (size_t)b * 2560;
    for (int d = tid; d < ND; d += 256) { att2s[d] = ag[d]; wfas[d] = w_fa[d]; }
    __syncthreads();
    int w = tid >> 6, lane = tid & 63;
    int p0 = blockIdx.x * 28;
    const unsigned short* a1 = att1B + ((size_t)b * NP + p0) * ND;
    #pragma unroll
    for (int i = 0; i < 7; ++i) {
        int p = w + 4 * i;
        const unsigned short* row = a1 + (size_t)p * ND;
        float s = 0.f;
        #pragma unroll
        for (int j = 0; j < 2; ++j) {
            int d = j * 256 + lane * 4;
            uint2 u = *reinterpret_cast<const uint2*>(row + d);   // 4 bf16
            float v0 = b2f_lo(u.x), v1 = b2f_hi(u.x);
            float v2 = b2f_lo(u.y), v3 = b2f_hi(u.y);
            float4 a2 = *reinterpret_cast<const float4*>(&att2s[d]);
            float4 wf = *reinterpret_cast<const float4*>(&wfas[d]);
            s += fmaxf(v0 + a2.x, 0.f) * wf.x + fmaxf(v1 + a2.y, 0.f) * wf.y
               + fmaxf(v2 + a2.z, 0.f) * wf.z + fmaxf(v3 + a2.w, 0.f) * wf.w;
        }
        for (int off = 32; off > 0; off >>= 1) s += __shfl_down(s, off);
        if (lane == 0) e[(size_t)b * NP + p0 + p] = s + b_fa[0];
    }
}

// ---------------- k_awe: softmax + awe (bf16 enc) + gate -> xh gawe; alpha (grid 8 x 32) ----------------
__global__ __launch_bounds__(256) void k_awe(
    const unsigned short* __restrict__ encB, const int* __restrict__ dlens,
    const float* __restrict__ e, const float* __restrict__ attg,
    float* __restrict__ xh, float* __restrict__ out_alpha, int t)
{
    __shared__ float es[256];
    __shared__ float red[256];
    int kc = blockIdx.x, b = blockIdx.y, tid = threadIdx.x;
    float ev = -1e30f;
    if (tid < NP) { float v = e[(size_t)b * NP + tid]; es[tid] = v; ev = v; }
    red[tid] = ev; __syncthreads();
    for (int s2 = 128; s2 > 0; s2 >>= 1) { if (tid < s2) red[tid] = fmaxf(red[tid], red[tid + s2]); __syncthreads(); }
    float m = red[0]; __syncthreads();
    float xe = (tid < NP) ? expf(es[tid] - m) : 0.f;
    red[tid] = xe; __syncthreads();
    for (int s2 = 128; s2 > 0; s2 >>= 1) { if (tid < s2) red[tid] += red[tid + s2]; __syncthreads(); }
    float inv = 1.0f / red[0];
    __syncthreads();
    es[tid] = xe * inv;
    __syncthreads();

    int k = kc * 256 + tid;
    const unsigned short* ec = encB + (size_t)b * NP * NE + k;
    float s0 = 0.f, s1 = 0.f, s2v = 0.f, s3 = 0.f;
    #pragma unroll 4
    for (int p = 0; p < NP; p += 4) {
        s0 += es[p + 0] * b2f(ec[(size_t)(p + 0) * NE]);
        s1 += es[p + 1] * b2f(ec[(size_t)(p + 1) * NE]);
        s2v += es[p + 2] * b2f(ec[(size_t)(p + 2) * NE]);
        s3 += es[p + 3] * b2f(ec[(size_t)(p + 3) * NE]);
    }
    float awe = (s0 + s1) + (s2v + s3);
    float gp = attg[(size_t)b * 2560 + 512 + k];      // includes b_fb
    float gate = 1.f / (1.f + expf(-gp));
    xh[(size_t)b * 3072 + 512 + k] = gate * awe;
    if (kc == 0 && tid < NP) {
        bool live = (t < dlens[b]);
        out_alpha[((size_t)b * NT + t) * NP + tid] = live ? es[tid] : 0.f;
    }
}

// ---------------- k_gates: gawe-columns GEMM partials (128 blocks: 32 ntiles x 4 ksplit of 512) ----
__global__ __launch_bounds__(256) void k_gates(
    const float* __restrict__ xh, const float* __restrict__ W_ih,
    float* __restrict__ gpart)
{
    __shared__ float As[1024];
    __shared__ float Ws[64][33];
    int blk = blockIdx.x, tid = threadIdx.x;
    int nt = blk & 31, ks = blk >> 5;
    int n0 = nt * 64;
    int b4 = (tid / 32) * 4, nl = (tid % 32) * 2;
    float acc[4][2] = {};
    tile_body_uniW(xh + 512 + (size_t)ks * 512, 3072, W_ih + 512 + (size_t)ks * 512, 2560,
                   n0, 0, 512, As, Ws, acc, tid);
    float* Cp = gpart + (size_t)ks * NB * 2048;
    #pragma unroll
    for (int j = 0; j < 2; ++j)
        #pragma unroll
        for (int i = 0; i < 4; ++i)
            Cp[(size_t)(b4 + i) * 2048 + n0 + nl + j] = acc[i][j];
}

// ---------------- k_cell: reduce 6 partial slices + LSTM cell; hseq stored bf16 ----------------
__global__ __launch_bounds__(256) void k_cell(
    const float* __restrict__ gpart, const int* __restrict__ dlens,
    const float* __restrict__ b_ih, const float* __restrict__ b_hh,
    float* __restrict__ hc, unsigned short* __restrict__ hseqB, int t)
{
    int b = blockIdx.x;
    for (int d = threadIdx.x; d < ND; d += 256) {
        float g0 = b_ih[d] + b_hh[d];
        float g1 = b_ih[512 + d] + b_hh[512 + d];
        float g2 = b_ih[1024 + d] + b_hh[1024 + d];
        float g3 = b_ih[1536 + d] + b_hh[1536 + d];
        #pragma unroll
        for (int ks = 0; ks < 6; ++ks) {
            const float* gp = gpart + ((size_t)ks * NB + b) * 2048;
            g0 += gp[d]; g1 += gp[512 + d]; g2 += gp[1024 + d]; g3 += gp[1536 + d];
        }
        float ig = 1.f / (1.f + expf(-g0));
        float fg = 1.f / (1.f + expf(-g1));
        float gt = tanhf(g2);
        float og = 1.f / (1.f + expf(-g3));
        float c_old = hc[(size_t)b * 1024 + 512 + d];
        float c_new = fg * c_old + ig * gt;
        float h_new = og * tanhf(c_new);
        hseqB[((size_t)t * NB + b) * ND + d] = f2b(h_new);
        if (t < dlens[b]) {
            hc[(size_t)b * 1024 + d] = h_new;
            hc[(size_t)b * 1024 + 512 + d] = c_new;
        }
    }
}

// ---------------- launcher ----------------
extern "C" void kernel_launch(void* const* d_in, const int* in_sizes, int n_in,
                              void* d_out, int out_size, void* d_ws, size_t ws_size,
                              hipStream_t stream)
{
    const float* enc   = (const float*)d_in[0];
    const int*   caps  = (const int*)d_in[1];
    const int*   clens = (const int*)d_in[2];
    const float* emb_W = (const float*)d_in[3];
    const float* W_ea  = (const float*)d_in[4];
    const float* b_ea  = (const float*)d_in[5];
    const float* W_da  = (const float*)d_in[6];
    const float* b_da  = (const float*)d_in[7];
    const float* w_fa  = (const float*)d_in[8];
    const float* b_fa  = (const float*)d_in[9];
    const float* W_ih  = (const float*)d_in[10];
    const float* b_ih  = (const float*)d_in[11];
    const float* W_hh  = (const float*)d_in[12];
    const float* b_hh  = (const float*)d_in[13];
    const float* W_h0  = (const float*)d_in[14];
    const float* b_h0  = (const float*)d_in[15];
    const float* W_c0  = (const float*)d_in[16];
    const float* b_c0  = (const float*)d_in[17];
    const float* W_fb  = (const float*)d_in[18];
    const float* b_fb  = (const float*)d_in[19];
    const float* W_fc  = (const float*)d_in[20];
    const float* b_fc  = (const float*)d_in[21];

    float* out = (float*)d_out;
    float* out_alpha = out + (size_t)NB * NT * NV;

    int* iws    = (int*)d_ws;
    int* sind   = iws;
    int* dlens  = iws + 32;
    int* rowmap = iws + 64;
    int* mpad   = iws + 704;
    float* base = (float*)d_ws + 1024;
    float* mean_enc = base;                         // 65536
    float* hc    = mean_enc + NB * NE;              // 32768
    float* attg  = hc + NB * 1024;                  // 81920
    float* xh    = attg + NB * 2560;                // 98304
    float* e     = xh + NB * 3072;                  // 6272
    float* embS  = e + NB * NP;                     // 327680
    float* gpart = embS + (size_t)NT * NB * ND;     // 6*32*2048 = 393216 (spart at setup fits)
    unsigned short* att1B = (unsigned short*)(gpart + 6 * NB * 2048);   // 6272*512 bf16
    unsigned short* hseqB = att1B + (size_t)NB * NP * ND;               // 640*512 bf16
    unsigned short* encB  = hseqB + (size_t)NT * NB * ND;               // 32*196*2048 bf16

    k_sort<<<1, 64, 0, stream>>>(clens, sind, dlens, rowmap, mpad);
    k_zero<<<NB * NT, 256, 0, stream>>>(dlens, out);
    k_conv_enc<<<dim3(NB * NP * NE / 2048), 256, 0, stream>>>(enc, sind, encB);
    k_emb<<<dim3(NT, NB), 256, 0, stream>>>(caps, sind, emb_W, embS);
    k_mean<<<dim3(NE / 256, NB), 256, 0, stream>>>(enc, sind, mean_enc);
    gemm_skinny_split<<<dim3(16, 8), 256, 0, stream>>>(mean_enc, W_h0, W_c0, gpart);
    k_hc0<<<dim3(NB), 256, 0, stream>>>(gpart, b_h0, b_c0, hc);
    gemm_att1_mfma<<<dim3(832), 256, 0, stream>>>(enc, W_ea, b_ea, att1B, sind);

    for (int t = 0; t < NT; ++t) {
        k_phase1<<<dim3(104), 256, 0, stream>>>(hc, W_da, W_fb, b_da, b_fb,
                                                embS, W_ih, W_hh, attg, gpart, t);
        k_e<<<dim3(7, NB), 256, 0, stream>>>(att1B, attg, w_fa, b_fa, e);
        k_awe<<<dim3(8, NB), 256, 0, stream>>>(encB, dlens, e, attg, xh, out_alpha, t);
        k_gates<<<dim3(128), 256, 0, stream>>>(xh, W_ih, gpart);
        k_cell<<<dim3(NB), 256, 0, stream>>>(gpart, dlens, b_ih, b_hh, hc, hseqB, t);
    }

    gemm_preds_mfma<<<dim3(2560), 256, 0, stream>>>(hseqB, W_fc, b_fc, out, rowmap, mpad);
}